// Round 7
// baseline (504.677 us; speedup 1.0000x reference)
//
#include <hip/hip_runtime.h>
#include <math.h>

#define NATOMS 20000
#define NEDGES 400000
#define EMBD   256
#define NRBF   50
#define NGATE  10
#define FOUT   128
#define APB    8       // atoms per block in k_main
#define OUTERC 5.0f

#define RBF_D    (5.0f/49.0f)
#define RBF_INVD (49.0f/5.0f)
#define RBF_C2   (-0.5f*(49.0f/5.0f)*(49.0f/5.0f)*1.4426950408889634f)
#define PI_OVER_OUTER 0.62831853071795864769f

static __device__ __forceinline__ float softplusf(float x){
    return (x > 15.0f) ? x : __logf(1.0f + __expf(x));
}
// round-to-nearest-even bf16, result in HIGH 16 bits
static __device__ __forceinline__ unsigned bfr(float v){
    unsigned u = __float_as_uint(v);
    return (u + 0x7fffu + ((u >> 16) & 1u)) & 0xffff0000u;
}
#define BLO(u) __uint_as_float((u) << 16)
#define BHI(u) __uint_as_float((u) & 0xffff0000u)

// ===== k_ag: R/Q/sv rows (0..51) + Ti/Tj tables (52..251) + degree count (252..) ==
// k_ct's matmul blocks moved here: they depend only on emb/weights, not counts.
__global__ __launch_bounds__(256) void k_ag(
    const float* __restrict__ Wd, const float* __restrict__ Wdt,
    const float* __restrict__ bd, const float* __restrict__ bdt,
    const float* __restrict__ bgam, const float* __restrict__ Wgam,
    const float* __restrict__ Wexp, const float* __restrict__ bexp,
    const float* __restrict__ Wg, const float* __restrict__ Wn,
    const float* __restrict__ emb,
    const float* __restrict__ Wai, const float* __restrict__ bai,
    const float* __restrict__ Waj, const float* __restrict__ baj,
    const int* __restrict__ esrc, int* __restrict__ counts,
    float* __restrict__ R0, float* __restrict__ R1,
    float* __restrict__ Qg, float* __restrict__ Qn, float* __restrict__ sv,
    float* __restrict__ Ti0, float* __restrict__ Ti1,
    float* __restrict__ Tj0, float* __restrict__ Tj1)
{
    const int b = blockIdx.x, t = threadIdx.x;
    if (b >= 252) {
        int e = (b - 252) * 256 + t;
        if (e < NEDGES) atomicAdd(&counts[esrc[e]], 1);
        return;
    }
    __shared__ float ya[256], za[256];
    if (b >= 52) {
        // ---- Ti/Tj tables (was k_ct blocks 1..200) ----
        const int side = (b >= 152);
        const int m = side ? b - 152 : b - 52;
        const float* er = emb + m*EMBD;
        const float* W1 = side ? Waj : Wai;
        const float* b1 = side ? baj : bai;
        float s = b1[t];
        #pragma unroll 8
        for (int k = 0; k < EMBD; k++) s += er[k] * W1[k*EMBD + t];
        ya[t] = s;
        __syncthreads();
        const float* G = Wgam + (size_t)(side ? 512 : 256) * EMBD;
        s = 0.f;
        #pragma unroll 8
        for (int k = 0; k < EMBD; k++) s += ya[k] * G[k*EMBD + t];
        za[t] = s;
        __syncthreads();
        const int half = t >> 7, ff = t & 127;
        const float* WX = Wexp + (size_t)half*EMBD*FOUT;
        s = 0.f;
        #pragma unroll 8
        for (int k = 0; k < EMBD; k++) s += za[k] * WX[k*FOUT + ff];
        float* dst = side ? (half ? Tj1 : Tj0) : (half ? Ti1 : Ti0);
        dst[m*FOUT + ff] = s;
        return;
    }
    // ---- rows of Y=[Wd@Wdt(50); bd@Wdt; bdt] -> R/Q/sv ----
    const int m = b;
    float s;
    if (m < 50) {
        const float* wr = Wd + m*EMBD;
        s = 0.f;
        #pragma unroll 8
        for (int k = 0; k < EMBD; k++) s += wr[k] * Wdt[k*EMBD + t];
    } else if (m == 50) {
        s = 0.f;
        #pragma unroll 8
        for (int k = 0; k < EMBD; k++) s += bd[k] * Wdt[k*EMBD + t];
    } else {
        s = bdt[t];
    }
    ya[t] = s;
    __syncthreads();
    s = 0.f;
    #pragma unroll 8
    for (int k = 0; k < EMBD; k++) s += ya[k] * Wgam[k*EMBD + t];
    if (m == 51) s += bgam[t];
    za[t] = s;
    __syncthreads();
    const int half = t >> 7, ff = t & 127;
    const float* WX = Wexp + (size_t)half*EMBD*FOUT;
    s = 0.f;
    #pragma unroll 8
    for (int k = 0; k < EMBD; k++) s += za[k] * WX[k*FOUT + ff];
    if (m < 50)       (half ? R1 : R0)[m*FOUT + ff] = s;
    else if (m == 50) sv[half*FOUT + ff] = s;
    else              sv[256 + half*FOUT + ff] = s + bexp[half*FOUT + ff];
    if (t < 20) {
        const int tt = t % 10;
        const float* WT = (t < 10) ? Wg : Wn;
        float q = 0.f;
        #pragma unroll 8
        for (int k = 0; k < EMBD; k++) q += ya[k] * WT[k*NGATE + tt];
        if (m < 50) { float* Q = (t < 10) ? Qg : Qn; Q[m*12 + tt] = q; }
        else {
            int off = (m == 50) ? ((t < 10) ? 512 : 532) : ((t < 10) ? 522 : 542);
            sv[off + tt] = q;
            float* Q = (t < 10) ? Qg : Qn; Q[m*12 + tt] = 0.f;   // zero-pad rows 50,51
        }
    }
}

// ================= k_scan: exclusive scan of counts -> cursors (1 block) =========
__global__ __launch_bounds__(256) void k_scan(
    const int* __restrict__ counts, int* __restrict__ cursors)
{
    const int t = threadIdx.x;
    __shared__ int part[256];
    const int CH = (NATOMS + 255) / 256;
    int base = t * CH, s = 0;
    for (int i = 0; i < CH; i++) { int idx = base + i; if (idx < NATOMS) s += counts[idx]; }
    part[t] = s;
    __syncthreads();
    for (int d = 1; d < 256; d <<= 1) {
        int v = (t >= d) ? part[t - d] : 0;
        __syncthreads();
        part[t] += v;
        __syncthreads();
    }
    int run = (t == 0) ? 0 : part[t - 1];
    for (int i = 0; i < CH; i++) {
        int idx = base + i;
        if (idx < NATOMS) { cursors[idx] = run; run += counts[idx]; }
    }
}

// ================= k_edge: transform + 16B record CSR scatter ===================
// rec[p] = float4: { w fp32 | g0,g1 bf16x2 | ex,ey bf16x2 | ez bf16 hi }
// zdj[p] = zd (7 bits) | C as 24-bit fixed point << 7   (fp32-grade cutoff)
__global__ __launch_bounds__(256) void k_edge(
    const int* __restrict__ z, const int* __restrict__ esrc, const int* __restrict__ edst,
    const float* __restrict__ ew, const float* __restrict__ evec, const float* __restrict__ noise,
    const float* __restrict__ Qg, const float* __restrict__ Qn, const float* __restrict__ sv,
    int* __restrict__ cursors,
    float4* __restrict__ rec, unsigned* __restrict__ zdj)
{
    __shared__ float qgL[52*12], qnL[52*12];
    __shared__ float nbuf[256*11];
    __shared__ float vbuf[768];
    const int t = threadIdx.x;
    const int e0 = blockIdx.x * 256;

    for (int i = t; i < 52*12; i += 256) { qgL[i] = Qg[i]; qnL[i] = Qn[i]; }
    #pragma unroll
    for (int q = 0; q < 10; q++) {
        int idx = q*256 + t; long long g = (long long)e0*10 + idx;
        if (g < (long long)NEDGES*10) { int r_ = idx/10; nbuf[r_*11 + (idx - r_*10)] = noise[g]; }
    }
    #pragma unroll
    for (int q = 0; q < 3; q++) {
        int idx = q*256 + t; long long g = (long long)e0*3 + idx;
        if (g < (long long)NEDGES*3) vbuf[idx] = evec[g];
    }
    __syncthreads();

    int e = e0 + t;
    if (e >= NEDGES) return;
    float w = ew[e];
    float C = (w < OUTERC) ? 0.5f*(__cosf(w*PI_OVER_OUTER) + 1.0f) : 0.0f;
    int iw = (int)(w * RBF_INVD);
    int j0 = (iw - 4) & ~3;
    j0 = max(0, min(40, j0));
    float rW[12];
    #pragma unroll
    for (int k = 0; k < 12; k++) { float tt = w - (j0+k)*RBF_D; rW[k] = exp2f(RBF_C2*tt*tt); }
    float hg[NGATE], hn[NGATE];
    #pragma unroll
    for (int g2 = 0; g2 < NGATE; g2++) { hg[g2] = 0.f; hn[g2] = 0.f; }
    #pragma unroll
    for (int k = 0; k < 12; k++) {
        float rk = rW[k];
        const float* qg = &qgL[(j0+k)*12];
        const float* qn = &qnL[(j0+k)*12];
        float4 ga = *(const float4*)qg; float4 gb = *(const float4*)(qg+4);
        float2 gc = *(const float2*)(qg+8);
        float4 na = *(const float4*)qn; float4 nb = *(const float4*)(qn+4);
        float2 nc = *(const float2*)(qn+8);
        hg[0]=fmaf(rk,ga.x,hg[0]); hg[1]=fmaf(rk,ga.y,hg[1]); hg[2]=fmaf(rk,ga.z,hg[2]); hg[3]=fmaf(rk,ga.w,hg[3]);
        hg[4]=fmaf(rk,gb.x,hg[4]); hg[5]=fmaf(rk,gb.y,hg[5]); hg[6]=fmaf(rk,gb.z,hg[6]); hg[7]=fmaf(rk,gb.w,hg[7]);
        hg[8]=fmaf(rk,gc.x,hg[8]); hg[9]=fmaf(rk,gc.y,hg[9]);
        hn[0]=fmaf(rk,na.x,hn[0]); hn[1]=fmaf(rk,na.y,hn[1]); hn[2]=fmaf(rk,na.z,hn[2]); hn[3]=fmaf(rk,na.w,hn[3]);
        hn[4]=fmaf(rk,nb.x,hn[4]); hn[5]=fmaf(rk,nb.y,hn[5]); hn[6]=fmaf(rk,nb.z,hn[6]); hn[7]=fmaf(rk,nb.w,hn[7]);
        hn[8]=fmaf(rk,nc.x,hn[8]); hn[9]=fmaf(rk,nc.y,hn[9]);
    }
    float H[NGATE];
    #pragma unroll
    for (int g2 = 0; g2 < NGATE; g2++) {
        float gv = C*(hg[g2] + sv[512+g2]) + sv[522+g2];
        float nv = C*(hn[g2] + sv[532+g2]) + sv[542+g2];
        H[g2] = gv + nbuf[t*11 + g2] * softplusf(nv);
    }
    float m1 = -INFINITY, m2 = -INFINITY;
    #pragma unroll
    for (int g2 = 0; g2 < NGATE; g2++) {
        float v = H[g2];
        if (v > m1) { m2 = m1; m1 = v; } else if (v > m2) { m2 = v; }
    }
    float den = 0.f;
    #pragma unroll
    for (int g2 = 0; g2 < NGATE; g2++) den += (H[g2] >= m2) ? __expf(H[g2] - m1) : 0.f;
    float inv = 1.0f / den;
    float g0 = inv;
    float g1 = __expf(m2 - m1) * inv;

    float ex = vbuf[t*3+0], ey = vbuf[t*3+1], ez = vbuf[t*3+2];
    float rn = rsqrtf(ex*ex + ey*ey + ez*ez);
    ex *= rn; ey *= rn; ez *= rn;
    int zd = z[edst[e]];
    int p = atomicAdd(&cursors[esrc[e]], 1);

    rec[p] = make_float4(w,
        __uint_as_float((bfr(g0)>>16) | bfr(g1)),
        __uint_as_float((bfr(ex)>>16) | bfr(ey)),
        __uint_as_float(bfr(ez)));
    zdj[p] = (unsigned)zd | (__float2uint_rn(C * 16777215.0f) << 7);
}

// ================= k_main v5: round-6 structure, APB=8, split dot phase =========
// Block = 320 (5 waves): 4 f-waves (per-thread (pair,f) slot) + 1 slot wave
// (lane l<52 owns j=l, 8 P regs, one exp2/edge). Disjoint LDS writers, no atomics.
// APB=8 amortizes the per-block dot phase + prologue over 2x atoms; the dot runs
// as TWO sequential half-passes (atoms 0-3 then 4-7) reusing 16 D regs to avoid
// the r5 spill pathology (round-5 lesson: >80 live regs => scratch => 4x loss).
#define FFLUSH() { \
    accS[aCur-aBeg][pair][f] = make_float4(accA, accX, accY, accZ); \
    accA=accX=accY=accZ=0.f; \
    aCur++; \
    if (aCur < aEnd) { nextEnd = neNxt; int an_ = aCur + 1; if (an_ < aEnd) neNxt = cursors[an_]; } \
    else nextEnd = 0x7fffffff; }

#define FCOMP(GI, D, TJ) { \
    int gi = (GI); \
    while (gi == nextEnd) FFLUSH() \
    unsigned gu = __float_as_uint(D.y), xu = __float_as_uint(D.z), eu = __float_as_uint(D.w); \
    float u_ = (pair ? BHI(gu) : BLO(gu)) * (TJ); \
    accA += u_; \
    accX = fmaf(BLO(xu), u_, accX); \
    accY = fmaf(BHI(xu), u_, accY); \
    accZ = fmaf(BHI(eu), u_, accZ); }

#define SFLUSH() { \
    int aIdx_ = aCur - aBeg; \
    if (sAct) { \
        *(float4*)&Plds[0][l][aIdx_*4] = make_float4(p00,p10,p20,p30); \
        *(float4*)&Plds[1][l][aIdx_*4] = make_float4(p01,p11,p21,p31); \
        p00=p01=p10=p11=p20=p21=p30=p31=0.f; } \
    aCur++; \
    if (aCur < aEnd) { nextEnd = neNxt; int an_ = aCur + 1; if (an_ < aEnd) neNxt = cursors[an_]; } \
    else nextEnd = 0x7fffffff; }

#define SCOMP(GI, D, CZ) { \
    int gi = (GI); \
    while (gi == nextEnd) SFLUSH() \
    unsigned gu = __float_as_uint(D.y), xu = __float_as_uint(D.z), eu = __float_as_uint(D.w); \
    float g0f = BLO(gu), g1f = BHI(gu); \
    float exf = BLO(xu), eyf = BHI(xu), ezf = BHI(eu); \
    float Cc_ = __uint2float_rn((CZ) >> 7) * (1.0f/16777215.0f); \
    float t_ = D.x - sjf; \
    float e2_ = exp2f(RBF_C2*t_*t_); \
    float b_ = isG ? Cc_*e2_ : (isC ? Cc_ : 1.0f); \
    float bg0 = b_*g0f, bg1 = b_*g1f; \
    p00 += bg0; p01 += bg1; \
    p10 = fmaf(exf,bg0,p10); p11 = fmaf(exf,bg1,p11); \
    p20 = fmaf(eyf,bg0,p20); p21 = fmaf(eyf,bg1,p21); \
    p30 = fmaf(ezf,bg0,p30); p31 = fmaf(ezf,bg1,p31); }

#define DOT16(PA,PB,PC,PD,R_) { \
    D00=fmaf(PA.x,R_,D00); D01=fmaf(PA.y,R_,D01); D02=fmaf(PA.z,R_,D02); D03=fmaf(PA.w,R_,D03); \
    D10=fmaf(PB.x,R_,D10); D11=fmaf(PB.y,R_,D11); D12=fmaf(PB.z,R_,D12); D13=fmaf(PB.w,R_,D13); \
    D20=fmaf(PC.x,R_,D20); D21=fmaf(PC.y,R_,D21); D22=fmaf(PC.z,R_,D22); D23=fmaf(PC.w,R_,D23); \
    D30=fmaf(PD.x,R_,D30); D31=fmaf(PD.y,R_,D31); D32=fmaf(PD.z,R_,D32); D33=fmaf(PD.w,R_,D33); }

__global__ __launch_bounds__(320) void k_main(
    const int* __restrict__ z, const int* __restrict__ cursors,
    const float4* __restrict__ rec, const unsigned* __restrict__ zdj,
    const float* __restrict__ R0, const float* __restrict__ R1,
    const float* __restrict__ Ti0, const float* __restrict__ Ti1,
    const float* __restrict__ Tj0, const float* __restrict__ Tj1,
    const float* __restrict__ sv, float* __restrict__ out)
{
    __shared__ float4 accS[APB][2][FOUT];                  // 32 KB, written by f-waves
    __shared__ __align__(16) float Plds[2][52][APB*4+4];   // 15 KB, written by slot wave
    const int tid = threadIdx.x;

    const int aBeg = blockIdx.x * APB, aEnd = aBeg + APB;
    const int eBeg = aBeg ? cursors[aBeg-1] : 0;
    const int eEnd = cursors[aEnd-1];

    int aCur = aBeg;
    int nextEnd = cursors[aCur];
    int neNxt = (aBeg+1 < aEnd) ? cursors[aBeg+1] : 0x7fffffff;

    const int pair = (tid >> 7) & 1, f = tid & 127;        // valid for tid<256

    if (tid < 256) {
        // ---------------- f-role stream (4 waves) ----------------
        const float* TjT = pair ? Tj1 : Tj0;
        float accA=0.f, accX=0.f, accY=0.f, accZ=0.f;

        unsigned czj0 = zdj[eBeg],   czj1 = zdj[eBeg+1];
        unsigned nzj0 = zdj[eBeg+2], nzj1 = zdj[eBeg+3];
        float4 c0 = rec[eBeg], c1 = rec[eBeg+1];
        float ctj0 = TjT[(czj0 & 0x7fu)*FOUT + f];
        float ctj1 = TjT[(czj1 & 0x7fu)*FOUT + f];

        for (int i = eBeg; i < eEnd; i += 2) {
            float4 n0 = rec[i+2], n1 = rec[i+3];
            float ntj0 = TjT[(nzj0 & 0x7fu)*FOUT + f];
            float ntj1 = TjT[(nzj1 & 0x7fu)*FOUT + f];
            unsigned mzj0 = zdj[i+4], mzj1 = zdj[i+5];

            FCOMP(i,   c0, ctj0)
            if (i + 1 < eEnd) { FCOMP(i+1, c1, ctj1) }

            c0 = n0; c1 = n1;
            czj0 = nzj0; czj1 = nzj1; nzj0 = mzj0; nzj1 = mzj1;
            ctj0 = ntj0; ctj1 = ntj1;
        }
        while (aCur < aEnd) FFLUSH();
    } else {
        // ---------------- slot-role stream (1 wave) ----------------
        const int l = tid - 256;
        const bool sAct = (l < 52);
        const bool isG = (l < 50), isC = (l == 50);
        const float sjf = l * RBF_D;
        float p00=0,p01=0,p10=0,p11=0,p20=0,p21=0,p30=0,p31=0;

        float4 c0 = rec[eBeg], c1 = rec[eBeg+1];
        unsigned z0 = zdj[eBeg], z1 = zdj[eBeg+1];

        for (int i = eBeg; i < eEnd; i += 2) {
            float4 n0 = rec[i+2], n1 = rec[i+3];
            unsigned y0 = zdj[i+2], y1 = zdj[i+3];

            SCOMP(i,   c0, z0)
            if (i + 1 < eEnd) { SCOMP(i+1, c1, z1) }

            c0 = n0; c1 = n1; z0 = y0; z1 = y1;
        }
        while (aCur < aEnd) SFLUSH();
    }
    __syncthreads();

    // ---- dot phase: two half-passes (atoms 0-3, 4-7), 16 D regs each ----
    if (tid < 256) {
        const float* Rtab = pair ? R1 : R0;
        const float* TiT  = pair ? Ti1 : Ti0;
        const float sVv = sv[pair*FOUT + f];
        const float dVv = sv[256 + pair*FOUT + f];
        #pragma unroll 1
        for (int ha = 0; ha < 2; ha++) {
            const int off = ha * 16;
            float D00=0,D01=0,D02=0,D03=0, D10=0,D11=0,D12=0,D13=0;
            float D20=0,D21=0,D22=0,D23=0, D30=0,D31=0,D32=0,D33=0;
            #pragma unroll 5
            for (int j = 0; j < 50; j++) {
                float r = Rtab[j*FOUT + f];
                const float* pb = &Plds[pair][j][off];
                float4 qa = *(const float4*)(pb+0);
                float4 qb = *(const float4*)(pb+4);
                float4 qc = *(const float4*)(pb+8);
                float4 qd = *(const float4*)(pb+12);
                DOT16(qa, qb, qc, qd, r)
            }
            {   // j = 50: constant row sV (weight C*g)
                const float* pb = &Plds[pair][50][off];
                float4 qa = *(const float4*)(pb+0);
                float4 qb = *(const float4*)(pb+4);
                float4 qc = *(const float4*)(pb+8);
                float4 qd = *(const float4*)(pb+12);
                DOT16(qa, qb, qc, qd, sVv)
            }
            {   // j = 51: per-atom row dV + Ti[z_a] (weight g)
                const float* pb = &Plds[pair][51][off];
                float4 qa = *(const float4*)(pb+0);
                float4 qb = *(const float4*)(pb+4);
                float4 qc = *(const float4*)(pb+8);
                float4 qd = *(const float4*)(pb+12);
                int ab = aBeg + ha*4;
                float r0 = dVv + TiT[z[ab+0]*FOUT + f];
                float r1 = dVv + TiT[z[ab+1]*FOUT + f];
                float r2 = dVv + TiT[z[ab+2]*FOUT + f];
                float r3 = dVv + TiT[z[ab+3]*FOUT + f];
                D00=fmaf(qa.x,r0,D00); D01=fmaf(qa.y,r0,D01); D02=fmaf(qa.z,r0,D02); D03=fmaf(qa.w,r0,D03);
                D10=fmaf(qb.x,r1,D10); D11=fmaf(qb.y,r1,D11); D12=fmaf(qb.z,r1,D12); D13=fmaf(qb.w,r1,D13);
                D20=fmaf(qc.x,r2,D20); D21=fmaf(qc.y,r2,D21); D22=fmaf(qc.z,r2,D22); D23=fmaf(qc.w,r2,D23);
                D30=fmaf(qd.x,r3,D30); D31=fmaf(qd.y,r3,D31); D32=fmaf(qd.z,r3,D32); D33=fmaf(qd.w,r3,D33);
            }
            const int a0 = ha*4;
            float4 t;
            t = accS[a0+0][pair][f]; t.x+=D00; t.y+=D01; t.z+=D02; t.w+=D03; accS[a0+0][pair][f] = t;
            t = accS[a0+1][pair][f]; t.x+=D10; t.y+=D11; t.z+=D12; t.w+=D13; accS[a0+1][pair][f] = t;
            t = accS[a0+2][pair][f]; t.x+=D20; t.y+=D21; t.z+=D22; t.w+=D23; accS[a0+2][pair][f] = t;
            t = accS[a0+3][pair][f]; t.x+=D30; t.y+=D31; t.z+=D32; t.w+=D33; accS[a0+3][pair][f] = t;
        }
    }
    __syncthreads();
    if (tid < FOUT) {
        #pragma unroll
        for (int a2 = 0; a2 < APB; a2++) {
            float4 v0 = accS[a2][0][tid];
            float4 v1 = accS[a2][1][tid];
            int atom = aBeg + a2;
            out[(size_t)atom*FOUT + tid] = v0.x + v1.x;
            float* vb = out + (size_t)NATOMS*FOUT + (size_t)atom*3*FOUT;
            vb[tid]        = v0.y + v1.y;
            vb[FOUT+tid]   = v0.z + v1.z;
            vb[2*FOUT+tid] = v0.w + v1.w;
        }
    }
}

extern "C" void kernel_launch(void* const* d_in, const int* in_sizes, int n_in,
                              void* d_out, int out_size, void* d_ws, size_t ws_size,
                              hipStream_t stream)
{
    const int*   z    = (const int*)d_in[0];
    const int*   ei   = (const int*)d_in[3];
    const int*   esrc = ei;
    const int*   edst = ei + NEDGES;
    const float* ew   = (const float*)d_in[4];
    const float* evec = (const float*)d_in[5];
    const float* nz   = (const float*)d_in[6];
    const float* emb  = (const float*)d_in[7];
    const float* Wd   = (const float*)d_in[8];
    const float* bd   = (const float*)d_in[9];
    const float* Wdt  = (const float*)d_in[10];
    const float* bdt  = (const float*)d_in[11];
    const float* Wai  = (const float*)d_in[12];
    const float* bai  = (const float*)d_in[13];
    const float* Waj  = (const float*)d_in[14];
    const float* baj  = (const float*)d_in[15];
    const float* Wgam = (const float*)d_in[16];
    const float* bgam = (const float*)d_in[17];
    const float* Wg   = (const float*)d_in[18];
    const float* Wn   = (const float*)d_in[19];
    const float* Wexp = (const float*)d_in[20];
    const float* bexp = (const float*)d_in[21];
    float* out = (float*)d_out;

    char* w = (char*)d_ws;
    auto alloc = [&](size_t bytes) -> void* {
        void* p = (void*)w;
        w += (bytes + 255) & ~(size_t)255;
        return p;
    };
    int*   counts  = (int*)alloc(NATOMS * 4);
    int*   cursors = (int*)alloc(NATOMS * 4);
    float* R0  = (float*)alloc(NRBF*FOUT*4);
    float* R1  = (float*)alloc(NRBF*FOUT*4);
    float* Qg  = (float*)alloc(52*12*4);
    float* Qn  = (float*)alloc(52*12*4);
    float* Ti0 = (float*)alloc(100*FOUT*4);
    float* Ti1 = (float*)alloc(100*FOUT*4);
    float* Tj0 = (float*)alloc(100*FOUT*4);
    float* Tj1 = (float*)alloc(100*FOUT*4);
    float* sv  = (float*)alloc(552*4);
    float4*   rec = (float4*)alloc(((size_t)NEDGES + 16)*16);  // +16 pad: prefetch over-reads <= +5
    unsigned* zdj = (unsigned*)alloc(((size_t)NEDGES + 16)*4);

    hipMemsetAsync(counts, 0, NATOMS*4, stream);
    hipMemsetAsync(rec + NEDGES, 0, 16*sizeof(float4), stream);   // zero pads (w=0)
    hipMemsetAsync(zdj + NEDGES, 0, 16*4, stream);                // zd=0, C=0

    {
        int grid = 252 + (NEDGES + 255) / 256;  // 1815
        k_ag<<<grid, 256, 0, stream>>>(Wd, Wdt, bd, bdt, bgam, Wgam, Wexp, bexp,
                                       Wg, Wn, emb, Wai, bai, Waj, baj,
                                       esrc, counts, R0, R1, Qg, Qn, sv,
                                       Ti0, Ti1, Tj0, Tj1);
    }
    k_scan<<<1, 256, 0, stream>>>(counts, cursors);
    {
        int grid = (NEDGES + 255) / 256;        // 1563
        k_edge<<<grid, 256, 0, stream>>>(z, esrc, edst, ew, evec, nz,
                                         Qg, Qn, sv, cursors, rec, zdj);
    }
    {
        int grid = NATOMS / APB;                // 2500
        k_main<<<grid, 320, 0, stream>>>(z, cursors, rec, zdj,
                                         R0, R1, Ti0, Ti1, Tj0, Tj1, sv, out);
    }
}

// Round 8
// 405.957 us; speedup vs baseline: 1.2432x; 1.2432x over previous
//
#include <hip/hip_runtime.h>
#include <math.h>

#define NATOMS 20000
#define NEDGES 400000
#define EMBD   256
#define NRBF   50
#define NGATE  10
#define FOUT   128
#define APB    4       // atoms per block in k_main
#define OUTERC 5.0f

#define RBF_D    (5.0f/49.0f)
#define RBF_INVD (49.0f/5.0f)
#define RBF_C2   (-0.5f*(49.0f/5.0f)*(49.0f/5.0f)*1.4426950408889634f)
#define PI_OVER_OUTER 0.62831853071795864769f

static __device__ __forceinline__ float softplusf(float x){
    return (x > 15.0f) ? x : __logf(1.0f + __expf(x));
}
// round-to-nearest-even bf16, result in HIGH 16 bits
static __device__ __forceinline__ unsigned bfr(float v){
    unsigned u = __float_as_uint(v);
    return (u + 0x7fffu + ((u >> 16) & 1u)) & 0xffff0000u;
}
#define BLO(u) __uint_as_float((u) << 16)
#define BHI(u) __uint_as_float((u) & 0xffff0000u)

// ===== k_ag: R/Q/sv rows (0..51) + Ti/Tj tables (52..251) + degree count (252..) ==
__global__ __launch_bounds__(256) void k_ag(
    const float* __restrict__ Wd, const float* __restrict__ Wdt,
    const float* __restrict__ bd, const float* __restrict__ bdt,
    const float* __restrict__ bgam, const float* __restrict__ Wgam,
    const float* __restrict__ Wexp, const float* __restrict__ bexp,
    const float* __restrict__ Wg, const float* __restrict__ Wn,
    const float* __restrict__ emb,
    const float* __restrict__ Wai, const float* __restrict__ bai,
    const float* __restrict__ Waj, const float* __restrict__ baj,
    const int* __restrict__ esrc, int* __restrict__ counts,
    float* __restrict__ R0, float* __restrict__ R1,
    float* __restrict__ Qg, float* __restrict__ Qn, float* __restrict__ sv,
    float* __restrict__ Ti0, float* __restrict__ Ti1,
    float* __restrict__ Tj0, float* __restrict__ Tj1)
{
    const int b = blockIdx.x, t = threadIdx.x;
    if (b >= 252) {
        int e = (b - 252) * 256 + t;
        if (e < NEDGES) atomicAdd(&counts[esrc[e]], 1);
        return;
    }
    __shared__ float ya[256], za[256];
    if (b >= 52) {
        // ---- Ti/Tj tables ----
        const int side = (b >= 152);
        const int m = side ? b - 152 : b - 52;
        const float* er = emb + m*EMBD;
        const float* W1 = side ? Waj : Wai;
        const float* b1 = side ? baj : bai;
        float s = b1[t];
        #pragma unroll 8
        for (int k = 0; k < EMBD; k++) s += er[k] * W1[k*EMBD + t];
        ya[t] = s;
        __syncthreads();
        const float* G = Wgam + (size_t)(side ? 512 : 256) * EMBD;
        s = 0.f;
        #pragma unroll 8
        for (int k = 0; k < EMBD; k++) s += ya[k] * G[k*EMBD + t];
        za[t] = s;
        __syncthreads();
        const int half = t >> 7, ff = t & 127;
        const float* WX = Wexp + (size_t)half*EMBD*FOUT;
        s = 0.f;
        #pragma unroll 8
        for (int k = 0; k < EMBD; k++) s += za[k] * WX[k*FOUT + ff];
        float* dst = side ? (half ? Tj1 : Tj0) : (half ? Ti1 : Ti0);
        dst[m*FOUT + ff] = s;
        return;
    }
    // ---- rows of Y=[Wd@Wdt(50); bd@Wdt; bdt] -> R/Q/sv ----
    const int m = b;
    float s;
    if (m < 50) {
        const float* wr = Wd + m*EMBD;
        s = 0.f;
        #pragma unroll 8
        for (int k = 0; k < EMBD; k++) s += wr[k] * Wdt[k*EMBD + t];
    } else if (m == 50) {
        s = 0.f;
        #pragma unroll 8
        for (int k = 0; k < EMBD; k++) s += bd[k] * Wdt[k*EMBD + t];
    } else {
        s = bdt[t];
    }
    ya[t] = s;
    __syncthreads();
    s = 0.f;
    #pragma unroll 8
    for (int k = 0; k < EMBD; k++) s += ya[k] * Wgam[k*EMBD + t];
    if (m == 51) s += bgam[t];
    za[t] = s;
    __syncthreads();
    const int half = t >> 7, ff = t & 127;
    const float* WX = Wexp + (size_t)half*EMBD*FOUT;
    s = 0.f;
    #pragma unroll 8
    for (int k = 0; k < EMBD; k++) s += za[k] * WX[k*FOUT + ff];
    if (m < 50)       (half ? R1 : R0)[m*FOUT + ff] = s;
    else if (m == 50) sv[half*FOUT + ff] = s;
    else              sv[256 + half*FOUT + ff] = s + bexp[half*FOUT + ff];
    if (t < 20) {
        const int tt = t % 10;
        const float* WT = (t < 10) ? Wg : Wn;
        float q = 0.f;
        #pragma unroll 8
        for (int k = 0; k < EMBD; k++) q += ya[k] * WT[k*NGATE + tt];
        if (m < 50) { float* Q = (t < 10) ? Qg : Qn; Q[m*12 + tt] = q; }
        else {
            int off = (m == 50) ? ((t < 10) ? 512 : 532) : ((t < 10) ? 522 : 542);
            sv[off + tt] = q;
            float* Q = (t < 10) ? Qg : Qn; Q[m*12 + tt] = 0.f;   // zero-pad rows 50,51
        }
    }
}

// ================= k_scan: exclusive scan of counts -> cursors (1 block) =========
__global__ __launch_bounds__(256) void k_scan(
    const int* __restrict__ counts, int* __restrict__ cursors)
{
    const int t = threadIdx.x;
    __shared__ int part[256];
    const int CH = (NATOMS + 255) / 256;
    int base = t * CH, s = 0;
    for (int i = 0; i < CH; i++) { int idx = base + i; if (idx < NATOMS) s += counts[idx]; }
    part[t] = s;
    __syncthreads();
    for (int d = 1; d < 256; d <<= 1) {
        int v = (t >= d) ? part[t - d] : 0;
        __syncthreads();
        part[t] += v;
        __syncthreads();
    }
    int run = (t == 0) ? 0 : part[t - 1];
    for (int i = 0; i < CH; i++) {
        int idx = base + i;
        if (idx < NATOMS) { cursors[idx] = run; run += counts[idx]; }
    }
}

// ================= k_edge: transform + 16B record CSR scatter ===================
// rec[p] = float4: { w fp32 | g0,g1 bf16x2 | ex,ey bf16x2 | ez bf16 hi }
// zdj[p] = zd (7 bits) | C as 24-bit fixed point << 7   (fp32-grade cutoff)
__global__ __launch_bounds__(256) void k_edge(
    const int* __restrict__ z, const int* __restrict__ esrc, const int* __restrict__ edst,
    const float* __restrict__ ew, const float* __restrict__ evec, const float* __restrict__ noise,
    const float* __restrict__ Qg, const float* __restrict__ Qn, const float* __restrict__ sv,
    int* __restrict__ cursors,
    float4* __restrict__ rec, unsigned* __restrict__ zdj)
{
    __shared__ float qgL[52*12], qnL[52*12];
    __shared__ float nbuf[256*11];
    __shared__ float vbuf[768];
    const int t = threadIdx.x;
    const int e0 = blockIdx.x * 256;

    for (int i = t; i < 52*12; i += 256) { qgL[i] = Qg[i]; qnL[i] = Qn[i]; }
    #pragma unroll
    for (int q = 0; q < 10; q++) {
        int idx = q*256 + t; long long g = (long long)e0*10 + idx;
        if (g < (long long)NEDGES*10) { int r_ = idx/10; nbuf[r_*11 + (idx - r_*10)] = noise[g]; }
    }
    #pragma unroll
    for (int q = 0; q < 3; q++) {
        int idx = q*256 + t; long long g = (long long)e0*3 + idx;
        if (g < (long long)NEDGES*3) vbuf[idx] = evec[g];
    }
    __syncthreads();

    int e = e0 + t;
    if (e >= NEDGES) return;
    float w = ew[e];
    float C = (w < OUTERC) ? 0.5f*(__cosf(w*PI_OVER_OUTER) + 1.0f) : 0.0f;
    int iw = (int)(w * RBF_INVD);
    int j0 = (iw - 4) & ~3;
    j0 = max(0, min(40, j0));
    float rW[12];
    #pragma unroll
    for (int k = 0; k < 12; k++) { float tt = w - (j0+k)*RBF_D; rW[k] = exp2f(RBF_C2*tt*tt); }
    float hg[NGATE], hn[NGATE];
    #pragma unroll
    for (int g2 = 0; g2 < NGATE; g2++) { hg[g2] = 0.f; hn[g2] = 0.f; }
    #pragma unroll
    for (int k = 0; k < 12; k++) {
        float rk = rW[k];
        const float* qg = &qgL[(j0+k)*12];
        const float* qn = &qnL[(j0+k)*12];
        float4 ga = *(const float4*)qg; float4 gb = *(const float4*)(qg+4);
        float2 gc = *(const float2*)(qg+8);
        float4 na = *(const float4*)qn; float4 nb = *(const float4*)(qn+4);
        float2 nc = *(const float2*)(qn+8);
        hg[0]=fmaf(rk,ga.x,hg[0]); hg[1]=fmaf(rk,ga.y,hg[1]); hg[2]=fmaf(rk,ga.z,hg[2]); hg[3]=fmaf(rk,ga.w,hg[3]);
        hg[4]=fmaf(rk,gb.x,hg[4]); hg[5]=fmaf(rk,gb.y,hg[5]); hg[6]=fmaf(rk,gb.z,hg[6]); hg[7]=fmaf(rk,gb.w,hg[7]);
        hg[8]=fmaf(rk,gc.x,hg[8]); hg[9]=fmaf(rk,gc.y,hg[9]);
        hn[0]=fmaf(rk,na.x,hn[0]); hn[1]=fmaf(rk,na.y,hn[1]); hn[2]=fmaf(rk,na.z,hn[2]); hn[3]=fmaf(rk,na.w,hn[3]);
        hn[4]=fmaf(rk,nb.x,hn[4]); hn[5]=fmaf(rk,nb.y,hn[5]); hn[6]=fmaf(rk,nb.z,hn[6]); hn[7]=fmaf(rk,nb.w,hn[7]);
        hn[8]=fmaf(rk,nc.x,hn[8]); hn[9]=fmaf(rk,nc.y,hn[9]);
    }
    float H[NGATE];
    #pragma unroll
    for (int g2 = 0; g2 < NGATE; g2++) {
        float gv = C*(hg[g2] + sv[512+g2]) + sv[522+g2];
        float nv = C*(hn[g2] + sv[532+g2]) + sv[542+g2];
        H[g2] = gv + nbuf[t*11 + g2] * softplusf(nv);
    }
    float m1 = -INFINITY, m2 = -INFINITY;
    #pragma unroll
    for (int g2 = 0; g2 < NGATE; g2++) {
        float v = H[g2];
        if (v > m1) { m2 = m1; m1 = v; } else if (v > m2) { m2 = v; }
    }
    float den = 0.f;
    #pragma unroll
    for (int g2 = 0; g2 < NGATE; g2++) den += (H[g2] >= m2) ? __expf(H[g2] - m1) : 0.f;
    float inv = 1.0f / den;
    float g0 = inv;
    float g1 = __expf(m2 - m1) * inv;

    float ex = vbuf[t*3+0], ey = vbuf[t*3+1], ez = vbuf[t*3+2];
    float rn = rsqrtf(ex*ex + ey*ey + ez*ez);
    ex *= rn; ey *= rn; ez *= rn;
    int zd = z[edst[e]];
    int p = atomicAdd(&cursors[esrc[e]], 1);

    rec[p] = make_float4(w,
        __uint_as_float((bfr(g0)>>16) | bfr(g1)),
        __uint_as_float((bfr(ex)>>16) | bfr(ey)),
        __uint_as_float(bfr(ez)));
    zdj[p] = (unsigned)zd | (__float2uint_rn(C * 16777215.0f) << 7);
}

// ================= k_main v6: round-6 structure + DEPTH-2 prefetch ==============
// r6 diagnosis: ~1000 cy per 2-edge iteration vs ~100 cy issue => rec/Tj load
// latency (HBM ~900cy) exposed; depth-1 prefetch covers only ~100cy. This round:
// 4 edges in flight (rec i..i+5 live, Tj gather issued 2 iters early via zdj
// held 4-7 ahead). +~20 VGPR on f-wave, still <= the 64-reg 8-wave budget.
#define FFLUSH() { \
    accS[aCur-aBeg][pair][f] = make_float4(accA, accX, accY, accZ); \
    accA=accX=accY=accZ=0.f; \
    aCur++; \
    if (aCur < aEnd) { nextEnd = neNxt; int an_ = aCur + 1; if (an_ < aEnd) neNxt = cursors[an_]; } \
    else nextEnd = 0x7fffffff; }

#define FCOMP(GI, D, TJ) { \
    int gi = (GI); \
    while (gi == nextEnd) FFLUSH() \
    unsigned gu = __float_as_uint(D.y), xu = __float_as_uint(D.z), eu = __float_as_uint(D.w); \
    float u_ = (pair ? BHI(gu) : BLO(gu)) * (TJ); \
    accA += u_; \
    accX = fmaf(BLO(xu), u_, accX); \
    accY = fmaf(BHI(xu), u_, accY); \
    accZ = fmaf(BHI(eu), u_, accZ); }

#define SFLUSH() { \
    int aIdx_ = aCur - aBeg; \
    if (sAct) { \
        *(float4*)&Plds[0][l][aIdx_*4] = make_float4(p00,p10,p20,p30); \
        *(float4*)&Plds[1][l][aIdx_*4] = make_float4(p01,p11,p21,p31); \
        p00=p01=p10=p11=p20=p21=p30=p31=0.f; } \
    aCur++; \
    if (aCur < aEnd) { nextEnd = neNxt; int an_ = aCur + 1; if (an_ < aEnd) neNxt = cursors[an_]; } \
    else nextEnd = 0x7fffffff; }

#define SCOMP(GI, D, CZ) { \
    int gi = (GI); \
    while (gi == nextEnd) SFLUSH() \
    unsigned gu = __float_as_uint(D.y), xu = __float_as_uint(D.z), eu = __float_as_uint(D.w); \
    float g0f = BLO(gu), g1f = BHI(gu); \
    float exf = BLO(xu), eyf = BHI(xu), ezf = BHI(eu); \
    float Cc_ = __uint2float_rn((CZ) >> 7) * (1.0f/16777215.0f); \
    float t_ = D.x - sjf; \
    float e2_ = exp2f(RBF_C2*t_*t_); \
    float b_ = isG ? Cc_*e2_ : (isC ? Cc_ : 1.0f); \
    float bg0 = b_*g0f, bg1 = b_*g1f; \
    p00 += bg0; p01 += bg1; \
    p10 = fmaf(exf,bg0,p10); p11 = fmaf(exf,bg1,p11); \
    p20 = fmaf(eyf,bg0,p20); p21 = fmaf(eyf,bg1,p21); \
    p30 = fmaf(ezf,bg0,p30); p31 = fmaf(ezf,bg1,p31); }

#define DOT16(PA,PB,PC,PD,R_) { \
    D00=fmaf(PA.x,R_,D00); D01=fmaf(PA.y,R_,D01); D02=fmaf(PA.z,R_,D02); D03=fmaf(PA.w,R_,D03); \
    D10=fmaf(PB.x,R_,D10); D11=fmaf(PB.y,R_,D11); D12=fmaf(PB.z,R_,D12); D13=fmaf(PB.w,R_,D13); \
    D20=fmaf(PC.x,R_,D20); D21=fmaf(PC.y,R_,D21); D22=fmaf(PC.z,R_,D22); D23=fmaf(PC.w,R_,D23); \
    D30=fmaf(PD.x,R_,D30); D31=fmaf(PD.y,R_,D31); D32=fmaf(PD.z,R_,D32); D33=fmaf(PD.w,R_,D33); }

__global__ __launch_bounds__(320) void k_main(
    const int* __restrict__ z, const int* __restrict__ cursors,
    const float4* __restrict__ rec, const unsigned* __restrict__ zdj,
    const float* __restrict__ R0, const float* __restrict__ R1,
    const float* __restrict__ Ti0, const float* __restrict__ Ti1,
    const float* __restrict__ Tj0, const float* __restrict__ Tj1,
    const float* __restrict__ sv, float* __restrict__ out)
{
    __shared__ float4 accS[APB][2][FOUT];                  // 16 KB, written by f-waves
    __shared__ __align__(16) float Plds[2][52][20];        // 8.3 KB, written by slot wave
    const int tid = threadIdx.x;

    const int aBeg = blockIdx.x * APB, aEnd = aBeg + APB;
    const int eBeg = aBeg ? cursors[aBeg-1] : 0;
    const int eEnd = cursors[aEnd-1];

    int aCur = aBeg;
    int nextEnd = cursors[aCur];
    int neNxt = (aBeg+1 < aEnd) ? cursors[aBeg+1] : 0x7fffffff;

    const int pair = (tid >> 7) & 1, f = tid & 127;        // valid for tid<256

    if (tid < 256) {
        // ---------------- f-role stream (4 waves), depth-2 pipeline ----------------
        const float* TjT = pair ? Tj1 : Tj0;
        float accA=0.f, accX=0.f, accY=0.f, accZ=0.f;

        float4 c0 = rec[eBeg],   c1 = rec[eBeg+1];
        float4 d0 = rec[eBeg+2], d1 = rec[eBeg+3];
        unsigned zj4 = zdj[eBeg+4], zj5 = zdj[eBeg+5];
        float ct0 = TjT[(zdj[eBeg]  & 0x7fu)*FOUT + f];
        float ct1 = TjT[(zdj[eBeg+1]& 0x7fu)*FOUT + f];
        float dt0 = TjT[(zdj[eBeg+2]& 0x7fu)*FOUT + f];
        float dt1 = TjT[(zdj[eBeg+3]& 0x7fu)*FOUT + f];

        for (int i = eBeg; i < eEnd; i += 2) {
            float4 e0 = rec[i+4], e1 = rec[i+5];
            unsigned zj6 = zdj[i+6], zj7 = zdj[i+7];
            float et0 = TjT[(zj4 & 0x7fu)*FOUT + f];
            float et1 = TjT[(zj5 & 0x7fu)*FOUT + f];

            FCOMP(i,   c0, ct0)
            if (i + 1 < eEnd) { FCOMP(i+1, c1, ct1) }

            c0 = d0; c1 = d1; d0 = e0; d1 = e1;
            ct0 = dt0; ct1 = dt1; dt0 = et0; dt1 = et1;
            zj4 = zj6; zj5 = zj7;
        }
        while (aCur < aEnd) FFLUSH();
    } else {
        // ---------------- slot-role stream (1 wave), depth-2 pipeline --------------
        const int l = tid - 256;
        const bool sAct = (l < 52);
        const bool isG = (l < 50), isC = (l == 50);
        const float sjf = l * RBF_D;
        float p00=0,p01=0,p10=0,p11=0,p20=0,p21=0,p30=0,p31=0;

        float4 c0 = rec[eBeg],   c1 = rec[eBeg+1];
        float4 d0 = rec[eBeg+2], d1 = rec[eBeg+3];
        unsigned z0 = zdj[eBeg],   z1 = zdj[eBeg+1];
        unsigned z2 = zdj[eBeg+2], z3 = zdj[eBeg+3];

        for (int i = eBeg; i < eEnd; i += 2) {
            float4 e0 = rec[i+4], e1 = rec[i+5];
            unsigned z4 = zdj[i+4], z5 = zdj[i+5];

            SCOMP(i,   c0, z0)
            if (i + 1 < eEnd) { SCOMP(i+1, c1, z1) }

            c0 = d0; c1 = d1; d0 = e0; d1 = e1;
            z0 = z2; z1 = z3; z2 = z4; z3 = z5;
        }
        while (aCur < aEnd) SFLUSH();
    }
    __syncthreads();

    // ---- dot phase: D[a][v] = sum_j P[pair][j][a*4+v] * row_j[f] ----
    if (tid < 256) {
        const float* Rtab = pair ? R1 : R0;
        const float* TiT  = pair ? Ti1 : Ti0;
        const float sVv = sv[pair*FOUT + f];
        const float dVv = sv[256 + pair*FOUT + f];
        float D00=0,D01=0,D02=0,D03=0, D10=0,D11=0,D12=0,D13=0;
        float D20=0,D21=0,D22=0,D23=0, D30=0,D31=0,D32=0,D33=0;
        #pragma unroll 5
        for (int j = 0; j < 50; j++) {
            float r = Rtab[j*FOUT + f];
            const float* pb = &Plds[pair][j][0];
            float4 qa = *(const float4*)(pb+0);
            float4 qb = *(const float4*)(pb+4);
            float4 qc = *(const float4*)(pb+8);
            float4 qd = *(const float4*)(pb+12);
            DOT16(qa, qb, qc, qd, r)
        }
        {   // j = 50: constant row sV (weight C*g)
            const float* pb = &Plds[pair][50][0];
            float4 qa = *(const float4*)(pb+0);
            float4 qb = *(const float4*)(pb+4);
            float4 qc = *(const float4*)(pb+8);
            float4 qd = *(const float4*)(pb+12);
            DOT16(qa, qb, qc, qd, sVv)
        }
        {   // j = 51: per-atom row dV + Ti[z_a] (weight g)
            const float* pb = &Plds[pair][51][0];
            float4 qa = *(const float4*)(pb+0);
            float4 qb = *(const float4*)(pb+4);
            float4 qc = *(const float4*)(pb+8);
            float4 qd = *(const float4*)(pb+12);
            float r0 = dVv + TiT[z[aBeg+0]*FOUT + f];
            float r1 = dVv + TiT[z[aBeg+1]*FOUT + f];
            float r2 = dVv + TiT[z[aBeg+2]*FOUT + f];
            float r3 = dVv + TiT[z[aBeg+3]*FOUT + f];
            D00=fmaf(qa.x,r0,D00); D01=fmaf(qa.y,r0,D01); D02=fmaf(qa.z,r0,D02); D03=fmaf(qa.w,r0,D03);
            D10=fmaf(qb.x,r1,D10); D11=fmaf(qb.y,r1,D11); D12=fmaf(qb.z,r1,D12); D13=fmaf(qb.w,r1,D13);
            D20=fmaf(qc.x,r2,D20); D21=fmaf(qc.y,r2,D21); D22=fmaf(qc.z,r2,D22); D23=fmaf(qc.w,r2,D23);
            D30=fmaf(qd.x,r3,D30); D31=fmaf(qd.y,r3,D31); D32=fmaf(qd.z,r3,D32); D33=fmaf(qd.w,r3,D33);
        }
        float4 t;
        t = accS[0][pair][f]; t.x+=D00; t.y+=D01; t.z+=D02; t.w+=D03; accS[0][pair][f] = t;
        t = accS[1][pair][f]; t.x+=D10; t.y+=D11; t.z+=D12; t.w+=D13; accS[1][pair][f] = t;
        t = accS[2][pair][f]; t.x+=D20; t.y+=D21; t.z+=D22; t.w+=D23; accS[2][pair][f] = t;
        t = accS[3][pair][f]; t.x+=D30; t.y+=D31; t.z+=D32; t.w+=D33; accS[3][pair][f] = t;
    }
    __syncthreads();
    if (tid < FOUT) {
        #pragma unroll
        for (int a2 = 0; a2 < APB; a2++) {
            float4 v0 = accS[a2][0][tid];
            float4 v1 = accS[a2][1][tid];
            int atom = aBeg + a2;
            out[(size_t)atom*FOUT + tid] = v0.x + v1.x;
            float* vb = out + (size_t)NATOMS*FOUT + (size_t)atom*3*FOUT;
            vb[tid]        = v0.y + v1.y;
            vb[FOUT+tid]   = v0.z + v1.z;
            vb[2*FOUT+tid] = v0.w + v1.w;
        }
    }
}

extern "C" void kernel_launch(void* const* d_in, const int* in_sizes, int n_in,
                              void* d_out, int out_size, void* d_ws, size_t ws_size,
                              hipStream_t stream)
{
    const int*   z    = (const int*)d_in[0];
    const int*   ei   = (const int*)d_in[3];
    const int*   esrc = ei;
    const int*   edst = ei + NEDGES;
    const float* ew   = (const float*)d_in[4];
    const float* evec = (const float*)d_in[5];
    const float* nz   = (const float*)d_in[6];
    const float* emb  = (const float*)d_in[7];
    const float* Wd   = (const float*)d_in[8];
    const float* bd   = (const float*)d_in[9];
    const float* Wdt  = (const float*)d_in[10];
    const float* bdt  = (const float*)d_in[11];
    const float* Wai  = (const float*)d_in[12];
    const float* bai  = (const float*)d_in[13];
    const float* Waj  = (const float*)d_in[14];
    const float* baj  = (const float*)d_in[15];
    const float* Wgam = (const float*)d_in[16];
    const float* bgam = (const float*)d_in[17];
    const float* Wg   = (const float*)d_in[18];
    const float* Wn   = (const float*)d_in[19];
    const float* Wexp = (const float*)d_in[20];
    const float* bexp = (const float*)d_in[21];
    float* out = (float*)d_out;

    char* w = (char*)d_ws;
    auto alloc = [&](size_t bytes) -> void* {
        void* p = (void*)w;
        w += (bytes + 255) & ~(size_t)255;
        return p;
    };
    int*   counts  = (int*)alloc(NATOMS * 4);
    int*   cursors = (int*)alloc(NATOMS * 4);
    float* R0  = (float*)alloc(NRBF*FOUT*4);
    float* R1  = (float*)alloc(NRBF*FOUT*4);
    float* Qg  = (float*)alloc(52*12*4);
    float* Qn  = (float*)alloc(52*12*4);
    float* Ti0 = (float*)alloc(100*FOUT*4);
    float* Ti1 = (float*)alloc(100*FOUT*4);
    float* Tj0 = (float*)alloc(100*FOUT*4);
    float* Tj1 = (float*)alloc(100*FOUT*4);
    float* sv  = (float*)alloc(552*4);
    float4*   rec = (float4*)alloc(((size_t)NEDGES + 16)*16);  // +16 pad: over-reads <= +8
    unsigned* zdj = (unsigned*)alloc(((size_t)NEDGES + 16)*4);

    hipMemsetAsync(counts, 0, NATOMS*4, stream);
    hipMemsetAsync(rec + NEDGES, 0, 16*sizeof(float4), stream);   // zero pads (w=0)
    hipMemsetAsync(zdj + NEDGES, 0, 16*4, stream);                // zd=0, C=0

    {
        int grid = 252 + (NEDGES + 255) / 256;  // 1815
        k_ag<<<grid, 256, 0, stream>>>(Wd, Wdt, bd, bdt, bgam, Wgam, Wexp, bexp,
                                       Wg, Wn, emb, Wai, bai, Waj, baj,
                                       esrc, counts, R0, R1, Qg, Qn, sv,
                                       Ti0, Ti1, Tj0, Tj1);
    }
    k_scan<<<1, 256, 0, stream>>>(counts, cursors);
    {
        int grid = (NEDGES + 255) / 256;        // 1563
        k_edge<<<grid, 256, 0, stream>>>(z, esrc, edst, ew, evec, nz,
                                         Qg, Qn, sv, cursors, rec, zdj);
    }
    {
        int grid = NATOMS / APB;                // 5000
        k_main<<<grid, 320, 0, stream>>>(z, cursors, rec, zdj,
                                         R0, R1, Ti0, Ti1, Tj0, Tj1, sv, out);
    }
}